// Round 1
// baseline (442.219 us; speedup 1.0000x reference)
//
#include <hip/hip_runtime.h>
#include <hip/hip_bf16.h>
#include <math.h>

// Problem constants
#define B_      4
#define T_      4096
#define D_      2048
#define DMEM_   1024
#define H_      16
#define DHEAD_  64
#define TABLE_  131072
#define NTOK    (B_ * T_)      // 16384 tokens
#define NKV     (2 * D_)       // 4096 (k rows then v rows of packed W / kv cols)
#define EPS_QK  1.1920928955078125e-07f
#define EPS_CONV 1e-5f

typedef __attribute__((ext_vector_type(8))) __bf16 bf16x8;
typedef __attribute__((ext_vector_type(4))) float  f32x4;

typedef __attribute__((address_space(3))) unsigned int       lds_u32;
typedef const __attribute__((address_space(1))) unsigned int glb_u32;

__device__ __forceinline__ unsigned short f2bf(float f) {
    unsigned u = __float_as_uint(f);
    u += 0x7fff + ((u >> 16) & 1);   // round-to-nearest-even
    return (unsigned short)(u >> 16);
}

__device__ __forceinline__ void gload16(const void* g, void* l) {
    __builtin_amdgcn_global_load_lds((glb_u32*)g, (lds_u32*)l, 16, 0, 0);
}

// ---------------------------------------------------------------------------
// 1) Gather: e[token, m] = emb_table[hash_ids[token,h] + h*TABLE][m&63]  (bf16)
//    grid = NTOK blocks, 256 thr; each thread one float4 (4 elems)
// ---------------------------------------------------------------------------
__global__ __launch_bounds__(256) void gather_e(
    const int* __restrict__ hash_ids, const float* __restrict__ table,
    unsigned short* __restrict__ e)
{
    const int token = blockIdx.x;
    const int m = threadIdx.x * 4;           // 0..1020
    const int h = m >> 6;
    const int w = m & 63;
    const long long row = (long long)hash_ids[token * H_ + h] + (long long)h * TABLE_;
    const float4 v = *(const float4*)(table + (size_t)row * DHEAD_ + w);
    ushort4 o;
    o.x = f2bf(v.x); o.y = f2bf(v.y); o.z = f2bf(v.z); o.w = f2bf(v.w);
    *(ushort4*)(e + (size_t)token * DMEM_ + m) = o;
}

// ---------------------------------------------------------------------------
// 2) Pack key_W/value_W into one bf16 [4096][1024] + bias [4096]
// ---------------------------------------------------------------------------
__global__ __launch_bounds__(256) void pack_w(
    const float* __restrict__ kW, const float* __restrict__ vW,
    const float* __restrict__ kb, const float* __restrict__ vb,
    unsigned short* __restrict__ Wp, float* __restrict__ biasP)
{
    const int idx4 = blockIdx.x * 256 + threadIdx.x;   // 0 .. NKV*256-1
    const int n = idx4 >> 8;
    const int m = (idx4 & 255) * 4;
    const float* src = (n < D_) ? (kW + (size_t)n * DMEM_) : (vW + (size_t)(n - D_) * DMEM_);
    const float4 v = *(const float4*)(src + m);
    ushort4 o;
    o.x = f2bf(v.x); o.y = f2bf(v.y); o.z = f2bf(v.z); o.w = f2bf(v.w);
    *(ushort4*)(Wp + (size_t)n * DMEM_ + m) = o;
    if (idx4 < NKV) biasP[idx4] = (idx4 < D_) ? kb[idx4] : vb[idx4 - D_];
}

// ---------------------------------------------------------------------------
// 3) GEMM: C[m,n] = sum_k A[m,k]*W[n,k] + bias[n]
//    A [NTOK][1024] bf16, W [4096][1024] bf16, C [NTOK][4096] f32
//    m97 structure: 128x128 tile, BK=64, 4 waves (2x2 of 64x64),
//    global_load_lds width 16, 2-barrier K loop, mfma 16x16x32 bf16.
// ---------------------------------------------------------------------------
#define BM 128
#define BN 128
#define BK 64

__global__ __launch_bounds__(256) void gemm_kv(
    const unsigned short* __restrict__ A,
    const unsigned short* __restrict__ W,
    const float* __restrict__ biasP,
    float* __restrict__ C)
{
    __shared__ unsigned short sA[BM * BK];
    __shared__ unsigned short sB[BN * BK];
    const int tid  = threadIdx.x;
    const int wid  = tid >> 6;
    const int lane = tid & 63;
    const int bn = blockIdx.x;   // 0..31  (N tiles)
    const int bm = blockIdx.y;   // 0..127 (M tiles)
    const int wm = wid >> 1;     // 0..1
    const int wn = wid & 1;      // 0..1

    const int ldrow = lane >> 3;        // 0..7
    const int ldkof = (lane & 7) * 8;   // element offset within BK row chunk

    const unsigned short* Abase = A + (size_t)(bm * BM) * DMEM_;
    const unsigned short* Wbase = W + (size_t)(bn * BN) * DMEM_;

    f32x4 acc[4][4] = {};

    for (int k0 = 0; k0 < DMEM_; k0 += BK) {
        // stage A and B tiles: each wave 4 chunks of 1024B per tile
#pragma unroll
        for (int c = 0; c < 4; ++c) {
            const int cc = c * 4 + wid;        // 0..15
            const int row = cc * 8 + ldrow;    // 0..127
            gload16(Abase + (size_t)row * DMEM_ + k0 + ldkof, &sA[cc * 512]);
            gload16(Wbase + (size_t)row * DMEM_ + k0 + ldkof, &sB[cc * 512]);
        }
        __syncthreads();
#pragma unroll
        for (int kk = 0; kk < 2; ++kk) {
            const int kpos = kk * 32 + (lane >> 4) * 8;
            bf16x8 af[4], bf[4];
#pragma unroll
            for (int i = 0; i < 4; ++i) {
                af[i] = *(const bf16x8*)&sA[(wm * 64 + i * 16 + (lane & 15)) * BK + kpos];
                bf[i] = *(const bf16x8*)&sB[(wn * 64 + i * 16 + (lane & 15)) * BK + kpos];
            }
#pragma unroll
            for (int mi = 0; mi < 4; ++mi)
#pragma unroll
                for (int ni = 0; ni < 4; ++ni)
                    acc[mi][ni] = __builtin_amdgcn_mfma_f32_16x16x32_bf16(
                        af[mi], bf[ni], acc[mi][ni], 0, 0, 0);
        }
        __syncthreads();
    }

    // epilogue: C/D layout col=lane&15, row=(lane>>4)*4+j
    const int row0 = bm * BM + wm * 64;
    const int col0 = bn * BN + wn * 64;
#pragma unroll
    for (int mi = 0; mi < 4; ++mi) {
#pragma unroll
        for (int ni = 0; ni < 4; ++ni) {
            const int r = row0 + mi * 16 + (lane >> 4) * 4;
            const int c = col0 + ni * 16 + (lane & 15);
            const float b = biasP[c];
#pragma unroll
            for (int j = 0; j < 4; ++j)
                C[(size_t)(r + j) * NKV + c] = acc[mi][ni][j] + b;
        }
    }
}

// ---------------------------------------------------------------------------
// 4) Row stats: per token compute gate and rinv
//    gate = sigmoid(sign(dot)*sqrt(max(|dot|,1e-6))),
//    dot  = sum(h*k*qg*kg) * rsqrt(mean h^2+eps) * rsqrt(mean k^2+eps) / sqrt(D)
//    rinv = rsqrt(gate^2 * mean(v^2) + 1e-5)
// ---------------------------------------------------------------------------
__global__ __launch_bounds__(256) void rowstats(
    const float* __restrict__ hid, const float* __restrict__ kv,
    const float* __restrict__ qg, const float* __restrict__ kg,
    float* __restrict__ gate, float* __restrict__ rinv)
{
    __shared__ float red[4][4];
    const int row = blockIdx.x;
    const int tid = threadIdx.x;
    const float4* h4 = (const float4*)(hid + (size_t)row * D_);
    const float4* k4 = (const float4*)(kv + (size_t)row * NKV);
    const float4* v4 = (const float4*)(kv + (size_t)row * NKV + D_);
    const float4* q4 = (const float4*)qg;
    const float4* g4 = (const float4*)kg;

    float sh2 = 0.f, sk2 = 0.f, shk = 0.f, sv2 = 0.f;
    for (int i = tid; i < D_ / 4; i += 256) {
        const float4 hv = h4[i], kk = k4[i], vv = v4[i], qv = q4[i], gv = g4[i];
        sh2 += hv.x*hv.x + hv.y*hv.y + hv.z*hv.z + hv.w*hv.w;
        sk2 += kk.x*kk.x + kk.y*kk.y + kk.z*kk.z + kk.w*kk.w;
        sv2 += vv.x*vv.x + vv.y*vv.y + vv.z*vv.z + vv.w*vv.w;
        shk += hv.x*kk.x*qv.x*gv.x + hv.y*kk.y*qv.y*gv.y
             + hv.z*kk.z*qv.z*gv.z + hv.w*kk.w*qv.w*gv.w;
    }
#pragma unroll
    for (int off = 32; off; off >>= 1) {
        sh2 += __shfl_xor(sh2, off);
        sk2 += __shfl_xor(sk2, off);
        shk += __shfl_xor(shk, off);
        sv2 += __shfl_xor(sv2, off);
    }
    const int wid = tid >> 6, lane = tid & 63;
    if (lane == 0) { red[wid][0] = sh2; red[wid][1] = sk2; red[wid][2] = shk; red[wid][3] = sv2; }
    __syncthreads();
    if (tid == 0) {
        sh2 = red[0][0] + red[1][0] + red[2][0] + red[3][0];
        sk2 = red[0][1] + red[1][1] + red[2][1] + red[3][1];
        shk = red[0][2] + red[1][2] + red[2][2] + red[3][2];
        sv2 = red[0][3] + red[1][3] + red[2][3] + red[3][3];
        const float invD = 1.0f / (float)D_;
        const float dot = shk * rsqrtf(sh2 * invD + EPS_QK) * rsqrtf(sk2 * invD + EPS_QK)
                          * (1.0f / sqrtf((float)D_));
        const float sgn = (dot > 0.f) ? 1.f : ((dot < 0.f) ? -1.f : 0.f);
        const float dd = sqrtf(fmaxf(fabsf(dot), 1e-6f)) * sgn;
        const float g = 1.f / (1.f + expf(-dd));
        gate[row] = g;
        rinv[row] = rsqrtf(g * g * (sv2 * invD) + EPS_CONV);
    }
}

// ---------------------------------------------------------------------------
// 5) Conv + output: out[t,d] = silu( sum_j w[d,j]*yn[t-6+2j,d] ) + gate[t]*v[t,d]
//    yn[tau,d] = gate[tau]*rinv[tau]*cg[d]*v[tau,d]
//    grid = NTOK*2 blocks (half row each), 256 thr, one float4/thread
// ---------------------------------------------------------------------------
__global__ __launch_bounds__(256) void convout(
    const float* __restrict__ kv, const float* __restrict__ gate,
    const float* __restrict__ rinv, const float* __restrict__ cg,
    const float* __restrict__ convw, float* __restrict__ out)
{
    const int bi  = blockIdx.x;
    const int row = bi >> 1;
    const int t   = row & (T_ - 1);
    const int d0  = (bi & 1) * 1024 + threadIdx.x * 4;

    const float4 v   = *(const float4*)(kv + (size_t)row * NKV + D_ + d0);
    const float  g0  = gate[row];
    const float4 cgv = *(const float4*)(cg + d0);
    // conv_w is [D][1][K=4]: per-d 4 taps, contiguous
    const float4 w0 = *(const float4*)(convw + (size_t)(d0 + 0) * 4);
    const float4 w1 = *(const float4*)(convw + (size_t)(d0 + 1) * 4);
    const float4 w2 = *(const float4*)(convw + (size_t)(d0 + 2) * 4);
    const float4 w3 = *(const float4*)(convw + (size_t)(d0 + 3) * 4);

    float acc0 = 0.f, acc1 = 0.f, acc2 = 0.f, acc3 = 0.f;
#pragma unroll
    for (int j = 0; j < 4; ++j) {
        const int tau = t - 6 + 2 * j;
        if (tau < 0) continue;                 // uniform per block
        const int rr = row - 6 + 2 * j;
        const float s = gate[rr] * rinv[rr];
        const float4 vj = *(const float4*)(kv + (size_t)rr * NKV + D_ + d0);
        const float wj0 = ((const float*)&w0)[j];
        const float wj1 = ((const float*)&w1)[j];
        const float wj2 = ((const float*)&w2)[j];
        const float wj3 = ((const float*)&w3)[j];
        acc0 += wj0 * s * cgv.x * vj.x;
        acc1 += wj1 * s * cgv.y * vj.y;
        acc2 += wj2 * s * cgv.z * vj.z;
        acc3 += wj3 * s * cgv.w * vj.w;
    }
    float4 o;
    o.x = acc0 / (1.f + expf(-acc0)) + g0 * v.x;
    o.y = acc1 / (1.f + expf(-acc1)) + g0 * v.y;
    o.z = acc2 / (1.f + expf(-acc2)) + g0 * v.z;
    o.w = acc3 / (1.f + expf(-acc3)) + g0 * v.w;
    *(float4*)(out + (size_t)row * D_ + d0) = o;
}

// ---------------------------------------------------------------------------
extern "C" void kernel_launch(void* const* d_in, const int* in_sizes, int n_in,
                              void* d_out, int out_size, void* d_ws, size_t ws_size,
                              hipStream_t stream) {
    const float* hid   = (const float*)d_in[0];
    const int*   hash  = (const int*)  d_in[1];
    const float* table = (const float*)d_in[2];
    const float* kW    = (const float*)d_in[3];
    const float* kb    = (const float*)d_in[4];
    const float* vW    = (const float*)d_in[5];
    const float* vb    = (const float*)d_in[6];
    const float* qg    = (const float*)d_in[7];
    const float* kg    = (const float*)d_in[8];
    const float* cg    = (const float*)d_in[9];
    const float* cw    = (const float*)d_in[10];
    float* out = (float*)d_out;

    char* ws = (char*)d_ws;
    unsigned short* e     = (unsigned short*)(ws);                 // 33,554,432 B
    unsigned short* Wp    = (unsigned short*)(ws + 33554432);      //  8,388,608 B
    float*          biasP = (float*)(ws + 41943040);               //     16,384 B
    float*          kvbuf = (float*)(ws + 41959424);               // 268,435,456 B
    float*          gateb = (float*)(ws + 310394880);              //     65,536 B
    float*          rinvb = (float*)(ws + 310460416);              //     65,536 B

    gather_e<<<dim3(NTOK), dim3(256), 0, stream>>>(hash, table, e);
    pack_w<<<dim3(NKV), dim3(256), 0, stream>>>(kW, vW, kb, vb, Wp, biasP);
    gemm_kv<<<dim3(NKV / BN, NTOK / BM), dim3(256), 0, stream>>>(e, Wp, biasP, kvbuf);
    rowstats<<<dim3(NTOK), dim3(256), 0, stream>>>(hid, kvbuf, qg, kg, gateb, rinvb);
    convout<<<dim3(NTOK * 2), dim3(256), 0, stream>>>(kvbuf, gateb, rinvb, cg, cw, out);
}

// Round 2
// 350.065 us; speedup vs baseline: 1.2632x; 1.2632x over previous
//
#include <hip/hip_runtime.h>
#include <hip/hip_bf16.h>
#include <math.h>

// Problem constants
#define B_      4
#define T_      4096
#define D_      2048
#define DMEM_   1024
#define H_      16
#define TABLE_  131072
#define NTOK    (B_ * T_)      // 16384 tokens
#define NKV     (2 * D_)       // 4096 packed k|v columns
#define NT_TILES 16            // K / 64
#define EPS_QK  1.1920928955078125e-07f
#define EPS_CONV 1e-5f

typedef __attribute__((ext_vector_type(8))) __bf16 bf16x8;
typedef __attribute__((ext_vector_type(4))) float  f32x4;

typedef __attribute__((address_space(3))) unsigned int       lds_u32;
typedef const __attribute__((address_space(1))) unsigned int glb_u32;

__device__ __forceinline__ unsigned short f2bf(float f) {
    unsigned u = __float_as_uint(f);
    u += 0x7fff + ((u >> 16) & 1);   // round-to-nearest-even
    return (unsigned short)(u >> 16);
}
__device__ __forceinline__ float bf2f(unsigned short u) {
    return __uint_as_float(((unsigned)u) << 16);
}
__device__ __forceinline__ void gload16(const void* g, void* l) {
    __builtin_amdgcn_global_load_lds((glb_u32*)g, (lds_u32*)l, 16, 0, 0);
}

// ---------------------------------------------------------------------------
// 1) Gather: e[token, m] = bf16(emb_table[hash_ids[token,h] + h*TABLE][m&63])
// ---------------------------------------------------------------------------
__global__ __launch_bounds__(256) void gather_e(
    const int* __restrict__ hash_ids, const float* __restrict__ table,
    unsigned short* __restrict__ e)
{
    const int token = blockIdx.x;
    const int m = threadIdx.x * 4;
    const int h = m >> 6;
    const int w = m & 63;
    const long long row = (long long)hash_ids[token * H_ + h] + (long long)h * TABLE_;
    const float4 v = *(const float4*)(table + (size_t)row * 64 + w);
    ushort4 o;
    o.x = f2bf(v.x); o.y = f2bf(v.y); o.z = f2bf(v.z); o.w = f2bf(v.w);
    *(ushort4*)(e + (size_t)token * DMEM_ + m) = o;
}

// ---------------------------------------------------------------------------
// 2) Pack key_W/value_W into one bf16 [4096][1024] + bias [4096]
// ---------------------------------------------------------------------------
__global__ __launch_bounds__(256) void pack_w(
    const float* __restrict__ kW, const float* __restrict__ vW,
    const float* __restrict__ kb, const float* __restrict__ vb,
    unsigned short* __restrict__ Wp, float* __restrict__ biasP)
{
    const int idx4 = blockIdx.x * 256 + threadIdx.x;
    const int n = idx4 >> 8;
    const int m = (idx4 & 255) * 4;
    const float* src = (n < D_) ? (kW + (size_t)n * DMEM_) : (vW + (size_t)(n - D_) * DMEM_);
    const float4 v = *(const float4*)(src + m);
    ushort4 o;
    o.x = f2bf(v.x); o.y = f2bf(v.y); o.z = f2bf(v.z); o.w = f2bf(v.w);
    *(ushort4*)(Wp + (size_t)n * DMEM_ + m) = o;
    if (idx4 < NKV) biasP[idx4] = (idx4 < D_) ? kb[idx4] : vb[idx4 - D_];
}

// ---------------------------------------------------------------------------
// 3) GEMM: kv[m,n] = bf16( sum_k A[m,k]*W[n,k] + bias[n] )
//    256x256 tile, BK=64, 8 waves (2Mx4N), 8-phase schedule (T2+T3+T4+T5),
//    st-swizzle byte^=(row&7)<<4 both-sides, vmcnt(6) counted, XCD swizzle.
//    LDS: A dbuf 2x32KB @0, B dbuf 2x32KB @64KB. Stage-half = 16KB:
//      A half mh: LDS tile-row l = mh*128 + wm*64 + r <-> global row wm*128+mh*64+r
//      B half nh: LDS tile-row l = nh*128 + wn*32 + r <-> global row wn*64+nh*32+r
//    Phase quadrants (mh,nh): (0,0),(0,1),(1,1),(1,0); per-phase stage targets
//    the region freed by the previous phase (derived liveness, see notes).
// ---------------------------------------------------------------------------
#define STAGE_A(dd, mh, ts) do { \
    const int ts_ = ((ts) < NT_TILES) ? (ts) : (NT_TILES - 1); \
    _Pragma("unroll") \
    for (int c_ = 0; c_ < 2; ++c_) { \
        const int lin_ = c_ * 512 + tid; \
        const int lr_ = lin_ >> 3, c16_ = lin_ & 7; \
        gload16(Ab + (size_t)((lr_ >> 6) * 128 + (mh) * 64 + (lr_ & 63)) * 2048 \
                   + ts_ * 128 + ((c16_ ^ (lr_ & 7)) << 4), \
                lds + (dd) * 32768 + (mh) * 16384 + (c_ * 512 + wid * 64) * 16); \
    } \
} while (0)

#define STAGE_B(dd, nh, ts) do { \
    const int ts_ = ((ts) < NT_TILES) ? (ts) : (NT_TILES - 1); \
    _Pragma("unroll") \
    for (int c_ = 0; c_ < 2; ++c_) { \
        const int lin_ = c_ * 512 + tid; \
        const int lr_ = lin_ >> 3, c16_ = lin_ & 7; \
        gload16(Wb + (size_t)((lr_ >> 5) * 64 + (nh) * 32 + (lr_ & 31)) * 2048 \
                   + ts_ * 128 + ((c16_ ^ (lr_ & 7)) << 4), \
                lds + 65536 + (dd) * 32768 + (nh) * 16384 + (c_ * 512 + wid * 64) * 16); \
    } \
} while (0)

#define LDA(dd, mh) do { \
    _Pragma("unroll") \
    for (int mi_ = 0; mi_ < 4; ++mi_) { \
        const int l_ = (mh) * 128 + wm * 64 + mi_ * 16 + (lane & 15); \
        _Pragma("unroll") \
        for (int kk_ = 0; kk_ < 2; ++kk_) { \
            const int kb_ = (kk_ * 64 + ((lane >> 4) << 4)) ^ ((lane & 7) << 4); \
            af[mi_][kk_] = *(const bf16x8*)(lds + (dd) * 32768 + l_ * 128 + kb_); \
        } \
    } \
} while (0)

#define LDB(dd, nh) do { \
    _Pragma("unroll") \
    for (int ni_ = 0; ni_ < 2; ++ni_) { \
        const int l_ = (nh) * 128 + wn * 32 + ni_ * 16 + (lane & 15); \
        _Pragma("unroll") \
        for (int kk_ = 0; kk_ < 2; ++kk_) { \
            const int kb_ = (kk_ * 64 + ((lane >> 4) << 4)) ^ ((lane & 7) << 4); \
            bfr[ni_][kk_] = *(const bf16x8*)(lds + 65536 + (dd) * 32768 + l_ * 128 + kb_); \
        } \
    } \
} while (0)

#define MM(mh, nh) do { \
    __builtin_amdgcn_s_setprio(1); \
    _Pragma("unroll") \
    for (int mi_ = 0; mi_ < 4; ++mi_) \
        _Pragma("unroll") \
        for (int ni_ = 0; ni_ < 2; ++ni_) \
            _Pragma("unroll") \
            for (int kk_ = 0; kk_ < 2; ++kk_) \
                acc[(mh) * 4 + mi_][(nh) * 2 + ni_] = \
                    __builtin_amdgcn_mfma_f32_16x16x32_bf16(af[mi_][kk_], bfr[ni_][kk_], \
                        acc[(mh) * 4 + mi_][(nh) * 2 + ni_], 0, 0, 0); \
    __builtin_amdgcn_s_setprio(0); \
} while (0)

#define BAR()  do { __builtin_amdgcn_sched_barrier(0); __builtin_amdgcn_s_barrier(); __builtin_amdgcn_sched_barrier(0); } while (0)
#define BARW() do { __builtin_amdgcn_sched_barrier(0); asm volatile("s_waitcnt lgkmcnt(0)" ::: "memory"); __builtin_amdgcn_s_barrier(); __builtin_amdgcn_sched_barrier(0); } while (0)
#define VMC(n) asm volatile("s_waitcnt vmcnt(" #n ")" ::: "memory")

#define K_TILE(dd, t) do { \
    bf16x8 af[4][2]; bf16x8 bfr[2][2]; \
    LDA(dd, 0); LDB(dd, 0); STAGE_B((dd) ^ 1, 0, (t) + 1); \
    BAR(); MM(0, 0); BAR(); \
    LDB(dd, 1); STAGE_A(dd, 0, (t) + 2); \
    BAR(); MM(0, 1); BAR(); \
    LDA(dd, 1); STAGE_B(dd, 1, (t) + 2); \
    BAR(); MM(1, 1); BAR(); \
    LDB(dd, 0); STAGE_A(dd, 1, (t) + 2); \
    VMC(6); BAR(); MM(1, 0); BAR(); \
} while (0)

__global__ __launch_bounds__(512, 2) void gemm_kv(
    const unsigned short* __restrict__ A,
    const unsigned short* __restrict__ W,
    const float* __restrict__ biasP,
    unsigned short* __restrict__ kv)
{
    __shared__ __align__(16) char lds[131072];
    const int tid  = threadIdx.x;
    const int wid  = tid >> 6;
    const int lane = tid & 63;
    const int bid  = blockIdx.x;
    const int swz  = (bid & 7) * 128 + (bid >> 3);   // XCD swizzle, 1024 % 8 == 0
    const int bm = swz >> 4, bn = swz & 15;          // 64 M-tiles x 16 N-tiles
    const int wm = wid >> 2, wn = wid & 3;           // 2 x 4 waves

    const char* Ab = (const char*)A + (size_t)bm * 256 * 2048;
    const char* Wb = (const char*)W + (size_t)bn * 256 * 2048;

    f32x4 acc[8][4] = {};

    // Prologue: tile0 fully + tile1 {A0,B1,A1}; B0(1) is staged in ph1(0).
    STAGE_A(0, 0, 0); STAGE_B(0, 0, 0); STAGE_B(0, 1, 0); STAGE_A(0, 1, 0);
    STAGE_A(1, 0, 1); STAGE_B(1, 1, 1); STAGE_A(1, 1, 1);
    VMC(6);   // tile-0's 4 halves landed (3 halves of tile-1 still in flight)
    BAR();

    for (int t = 0; t < NT_TILES; t += 2) {
        K_TILE(0, t);
        K_TILE(1, t + 1);
    }

    VMC(0);   // drain stragglers before reusing LDS
    BARW();

    // Epilogue: per frag-row mi, stage 32x256 bf16 slab in LDS, write 8B/lane.
    float breg[4];
#pragma unroll
    for (int ni = 0; ni < 4; ++ni)
        breg[ni] = biasP[bn * 256 + wn * 64 + ni * 16 + (lane & 15)];

#pragma unroll
    for (int mi = 0; mi < 8; ++mi) {
#pragma unroll
        for (int ni = 0; ni < 4; ++ni) {
#pragma unroll
            for (int j = 0; j < 4; ++j) {
                const int srow = wm * 16 + (lane >> 4) * 4 + j;
                const int colb = (wn * 64 + ni * 16 + (lane & 15)) * 2;
                *(unsigned short*)(lds + srow * 512 + (colb ^ (((srow >> 2) & 3) << 5))) =
                    f2bf(acc[mi][ni][j] + breg[ni]);
            }
        }
        BARW();
#pragma unroll
        for (int c2 = 0; c2 < 4; ++c2) {
            const int lin = c2 * 512 + tid;
            const int srow = lin >> 6, cb8 = (lin & 63) * 8;
            const ushort4 vv = *(const ushort4*)(lds + srow * 512 + (cb8 ^ (((srow >> 2) & 3) << 5)));
            const int grow = bm * 256 + (srow >> 4) * 128 + mi * 16 + (srow & 15);
            const int gcol = bn * 256 + (lin & 63) * 4;
            *(ushort4*)((char*)kv + (size_t)grow * 8192 + gcol * 2) = vv;
        }
        BARW();
    }
}

// ---------------------------------------------------------------------------
// 4) Row stats: gate and rinv per token (kv now bf16)
// ---------------------------------------------------------------------------
__global__ __launch_bounds__(256) void rowstats(
    const float* __restrict__ hid, const unsigned short* __restrict__ kv,
    const float* __restrict__ qg, const float* __restrict__ kg,
    float* __restrict__ gate, float* __restrict__ rinv)
{
    __shared__ float red[4][4];
    const int row = blockIdx.x;
    const int tid = threadIdx.x;
    const int d0 = tid * 8;                       // 256 thr x 8 = 2048

    const float* hrow = hid + (size_t)row * D_ + d0;
    const unsigned short* krow = kv + (size_t)row * NKV + d0;
    const unsigned short* vrow = krow + D_;

    const float4 ha = *(const float4*)hrow,        hb = *(const float4*)(hrow + 4);
    const ushort4 k4a = *(const ushort4*)krow,     k4b = *(const ushort4*)(krow + 4);
    const ushort4 v4a = *(const ushort4*)vrow,     v4b = *(const ushort4*)(vrow + 4);
    const float4 qa = *(const float4*)(qg + d0),   qb = *(const float4*)(qg + d0 + 4);
    const float4 ga = *(const float4*)(kg + d0),   gb = *(const float4*)(kg + d0 + 4);

    float h[8] = {ha.x, ha.y, ha.z, ha.w, hb.x, hb.y, hb.z, hb.w};
    float q[8] = {qa.x, qa.y, qa.z, qa.w, qb.x, qb.y, qb.z, qb.w};
    float g[8] = {ga.x, ga.y, ga.z, ga.w, gb.x, gb.y, gb.z, gb.w};
    float k[8] = {bf2f(k4a.x), bf2f(k4a.y), bf2f(k4a.z), bf2f(k4a.w),
                  bf2f(k4b.x), bf2f(k4b.y), bf2f(k4b.z), bf2f(k4b.w)};
    float v[8] = {bf2f(v4a.x), bf2f(v4a.y), bf2f(v4a.z), bf2f(v4a.w),
                  bf2f(v4b.x), bf2f(v4b.y), bf2f(v4b.z), bf2f(v4b.w)};

    float sh2 = 0.f, sk2 = 0.f, shk = 0.f, sv2 = 0.f;
#pragma unroll
    for (int i = 0; i < 8; ++i) {
        sh2 += h[i] * h[i];
        sk2 += k[i] * k[i];
        sv2 += v[i] * v[i];
        shk += h[i] * k[i] * q[i] * g[i];
    }
#pragma unroll
    for (int off = 32; off; off >>= 1) {
        sh2 += __shfl_xor(sh2, off);
        sk2 += __shfl_xor(sk2, off);
        shk += __shfl_xor(shk, off);
        sv2 += __shfl_xor(sv2, off);
    }
    const int wid = tid >> 6, lane = tid & 63;
    if (lane == 0) { red[wid][0] = sh2; red[wid][1] = sk2; red[wid][2] = shk; red[wid][3] = sv2; }
    __syncthreads();
    if (tid == 0) {
        sh2 = red[0][0] + red[1][0] + red[2][0] + red[3][0];
        sk2 = red[0][1] + red[1][1] + red[2][1] + red[3][1];
        shk = red[0][2] + red[1][2] + red[2][2] + red[3][2];
        sv2 = red[0][3] + red[1][3] + red[2][3] + red[3][3];
        const float invD = 1.0f / (float)D_;
        const float dot = shk * rsqrtf(sh2 * invD + EPS_QK) * rsqrtf(sk2 * invD + EPS_QK)
                          * (1.0f / sqrtf((float)D_));
        const float sgn = (dot > 0.f) ? 1.f : ((dot < 0.f) ? -1.f : 0.f);
        const float dd = sqrtf(fmaxf(fabsf(dot), 1e-6f)) * sgn;
        const float gg = 1.f / (1.f + expf(-dd));
        gate[row] = gg;
        rinv[row] = rsqrtf(gg * gg * (sv2 * invD) + EPS_CONV);
    }
}

// ---------------------------------------------------------------------------
// 5) Conv + output (v read as bf16)
// ---------------------------------------------------------------------------
__global__ __launch_bounds__(256) void convout(
    const unsigned short* __restrict__ kv, const float* __restrict__ gate,
    const float* __restrict__ rinv, const float* __restrict__ cg,
    const float* __restrict__ convw, float* __restrict__ out)
{
    const int row = blockIdx.x;
    const int t   = row & (T_ - 1);
    const int d0  = threadIdx.x * 8;

    const unsigned short* vrow = kv + (size_t)row * NKV + D_ + d0;
    const ushort4 v4a = *(const ushort4*)vrow, v4b = *(const ushort4*)(vrow + 4);
    float v[8] = {bf2f(v4a.x), bf2f(v4a.y), bf2f(v4a.z), bf2f(v4a.w),
                  bf2f(v4b.x), bf2f(v4b.y), bf2f(v4b.z), bf2f(v4b.w)};

    const float4 ca = *(const float4*)(cg + d0), cb = *(const float4*)(cg + d0 + 4);
    float cgv[8] = {ca.x, ca.y, ca.z, ca.w, cb.x, cb.y, cb.z, cb.w};

    float w[8][4];
#pragma unroll
    for (int ee = 0; ee < 8; ++ee) {
        const float4 wv = *(const float4*)(convw + (size_t)(d0 + ee) * 4);
        w[ee][0] = wv.x; w[ee][1] = wv.y; w[ee][2] = wv.z; w[ee][3] = wv.w;
    }

    float acc[8] = {};
#pragma unroll
    for (int j = 0; j < 4; ++j) {
        const int tau = t - 6 + 2 * j;
        if (tau < 0) continue;                 // uniform per block
        const int rr = row - 6 + 2 * j;
        const float s = gate[rr] * rinv[rr];
        const unsigned short* vj = kv + (size_t)rr * NKV + D_ + d0;
        const ushort4 a = *(const ushort4*)vj, b = *(const ushort4*)(vj + 4);
        float vv[8] = {bf2f(a.x), bf2f(a.y), bf2f(a.z), bf2f(a.w),
                       bf2f(b.x), bf2f(b.y), bf2f(b.z), bf2f(b.w)};
#pragma unroll
        for (int ee = 0; ee < 8; ++ee)
            acc[ee] += w[ee][j] * s * cgv[ee] * vv[ee];
    }

    const float g0 = gate[row];
    float o[8];
#pragma unroll
    for (int ee = 0; ee < 8; ++ee)
        o[ee] = acc[ee] / (1.f + expf(-acc[ee])) + g0 * v[ee];

    float* op = out + (size_t)row * D_ + d0;
    *(float4*)op       = make_float4(o[0], o[1], o[2], o[3]);
    *(float4*)(op + 4) = make_float4(o[4], o[5], o[6], o[7]);
}

// ---------------------------------------------------------------------------
extern "C" void kernel_launch(void* const* d_in, const int* in_sizes, int n_in,
                              void* d_out, int out_size, void* d_ws, size_t ws_size,
                              hipStream_t stream) {
    const float* hid   = (const float*)d_in[0];
    const int*   hash  = (const int*)  d_in[1];
    const float* table = (const float*)d_in[2];
    const float* kW    = (const float*)d_in[3];
    const float* kb    = (const float*)d_in[4];
    const float* vW    = (const float*)d_in[5];
    const float* vb    = (const float*)d_in[6];
    const float* qg    = (const float*)d_in[7];
    const float* kg    = (const float*)d_in[8];
    const float* cg    = (const float*)d_in[9];
    const float* cw    = (const float*)d_in[10];
    float* out = (float*)d_out;

    char* ws = (char*)d_ws;
    unsigned short* e     = (unsigned short*)(ws);                 //  33,554,432 B
    unsigned short* Wp    = (unsigned short*)(ws + 33554432);      //   8,388,608 B
    float*          biasP = (float*)(ws + 41943040);               //      16,384 B
    unsigned short* kvbuf = (unsigned short*)(ws + 41959424);      // 134,217,728 B (bf16)
    float*          gateb = (float*)(ws + 176177152);              //      65,536 B
    float*          rinvb = (float*)(ws + 176242688);              //      65,536 B

    gather_e<<<dim3(NTOK), dim3(256), 0, stream>>>(hash, table, e);
    pack_w<<<dim3(NKV), dim3(256), 0, stream>>>(kW, vW, kb, vb, Wp, biasP);
    gemm_kv<<<dim3(1024), dim3(512), 0, stream>>>(e, Wp, biasP, kvbuf);
    rowstats<<<dim3(NTOK), dim3(256), 0, stream>>>(hid, kvbuf, qg, kg, gateb, rinvb);
    convout<<<dim3(NTOK), dim3(256), 0, stream>>>(kvbuf, gateb, rinvb, cg, cw, out);
}

// Round 3
// 334.325 us; speedup vs baseline: 1.3227x; 1.0471x over previous
//
#include <hip/hip_runtime.h>
#include <hip/hip_bf16.h>
#include <math.h>

// Problem constants
#define B_      4
#define T_      4096
#define D_      2048
#define DMEM_   1024
#define H_      16
#define TABLE_  131072
#define NTOK    (B_ * T_)      // 16384 tokens
#define NKV     (2 * D_)       // 4096 packed k|v output columns
#define NT_TILES 16            // K / 64
#define EPS_QK  1.1920928955078125e-07f
#define EPS_CONV 1e-5f
#define INV_D   (1.0f / 2048.0f)
#define INV_SQRT_D 0.02209708691207961f   // 1/sqrt(2048)

typedef __attribute__((ext_vector_type(8))) __bf16 bf16x8;
typedef __attribute__((ext_vector_type(4))) float  f32x4;

typedef __attribute__((address_space(3))) unsigned int       lds_u32;
typedef const __attribute__((address_space(1))) unsigned int glb_u32;

__device__ __forceinline__ unsigned short f2bf(float f) {
    unsigned u = __float_as_uint(f);
    u += 0x7fff + ((u >> 16) & 1);   // round-to-nearest-even
    return (unsigned short)(u >> 16);
}
__device__ __forceinline__ float bf2f(unsigned short u) {
    return __uint_as_float(((unsigned)u) << 16);
}
__device__ __forceinline__ void gload16(const void* g, void* l) {
    __builtin_amdgcn_global_load_lds((glb_u32*)g, (lds_u32*)l, 16, 0, 0);
}

// ---------------------------------------------------------------------------
// 1) Gather: e[token, m] = bf16(emb_table[hash_ids[token,h] + h*TABLE][m&63])
// ---------------------------------------------------------------------------
__global__ __launch_bounds__(256) void gather_e(
    const int* __restrict__ hash_ids, const float* __restrict__ table,
    unsigned short* __restrict__ e)
{
    const int token = blockIdx.x;
    const int m = threadIdx.x * 4;
    const int h = m >> 6;
    const int w = m & 63;
    const long long row = (long long)hash_ids[token * H_ + h] + (long long)h * TABLE_;
    const float4 v = *(const float4*)(table + (size_t)row * 64 + w);
    ushort4 o;
    o.x = f2bf(v.x); o.y = f2bf(v.y); o.z = f2bf(v.z); o.w = f2bf(v.w);
    *(ushort4*)(e + (size_t)token * DMEM_ + m) = o;
}

// ---------------------------------------------------------------------------
// 2) Pack key_W/value_W into bf16 [4096][1024] + bias [4096] + qkg + zero stats
// ---------------------------------------------------------------------------
__global__ __launch_bounds__(256) void pack_w(
    const float* __restrict__ kW, const float* __restrict__ vW,
    const float* __restrict__ kb, const float* __restrict__ vb,
    const float* __restrict__ qg, const float* __restrict__ kg,
    unsigned short* __restrict__ Wp, float* __restrict__ biasP,
    float* __restrict__ qkg, float* __restrict__ gstats /* 4*NTOK floats */)
{
    const int idx4 = blockIdx.x * 256 + threadIdx.x;
    const int n = idx4 >> 8;
    const int m = (idx4 & 255) * 4;
    const float* src = (n < D_) ? (kW + (size_t)n * DMEM_) : (vW + (size_t)(n - D_) * DMEM_);
    const float4 v = *(const float4*)(src + m);
    ushort4 o;
    o.x = f2bf(v.x); o.y = f2bf(v.y); o.z = f2bf(v.z); o.w = f2bf(v.w);
    *(ushort4*)(Wp + (size_t)n * DMEM_ + m) = o;
    if (idx4 < NKV) biasP[idx4] = (idx4 < D_) ? kb[idx4] : vb[idx4 - D_];
    if (idx4 < D_)  qkg[idx4] = qg[idx4] * kg[idx4];
    if (idx4 < 4 * NTOK) gstats[idx4] = 0.0f;
}

// ---------------------------------------------------------------------------
// 3) GEMM: 256x256 tile, BK=64, 8 waves (2Mx4N), 8-phase (T2+T3+T4+T5).
//    bn<8  (k-half): reduce tile into per-row {h2,k2,hk} partials, no store.
//    bn>=8 (v-half): store bf16 v to vbuf[16384][2048] + per-row v2 partials.
// ---------------------------------------------------------------------------
#define STAGE_A(dd, mh, ts) do { \
    if ((ts) < NT_TILES) { \
        _Pragma("unroll") \
        for (int c_ = 0; c_ < 2; ++c_) { \
            const int lin_ = c_ * 512 + tid; \
            const int lr_ = lin_ >> 3, c16_ = lin_ & 7; \
            gload16(Ab + (size_t)((lr_ >> 6) * 128 + (mh) * 64 + (lr_ & 63)) * 2048 \
                       + (ts) * 128 + ((c16_ ^ (lr_ & 7)) << 4), \
                    lds + (dd) * 32768 + (mh) * 16384 + (c_ * 512 + wid * 64) * 16); \
        } \
    } \
} while (0)

#define STAGE_B(dd, nh, ts) do { \
    if ((ts) < NT_TILES) { \
        _Pragma("unroll") \
        for (int c_ = 0; c_ < 2; ++c_) { \
            const int lin_ = c_ * 512 + tid; \
            const int lr_ = lin_ >> 3, c16_ = lin_ & 7; \
            gload16(Wb + (size_t)((lr_ >> 5) * 64 + (nh) * 32 + (lr_ & 31)) * 2048 \
                       + (ts) * 128 + ((c16_ ^ (lr_ & 7)) << 4), \
                    lds + 65536 + (dd) * 32768 + (nh) * 16384 + (c_ * 512 + wid * 64) * 16); \
        } \
    } \
} while (0)

#define LDA(dd, mh) do { \
    _Pragma("unroll") \
    for (int mi_ = 0; mi_ < 4; ++mi_) { \
        const int l_ = (mh) * 128 + wm * 64 + mi_ * 16 + (lane & 15); \
        _Pragma("unroll") \
        for (int kk_ = 0; kk_ < 2; ++kk_) { \
            const int kb_ = (kk_ * 64 + ((lane >> 4) << 4)) ^ ((lane & 7) << 4); \
            af[mi_][kk_] = *(const bf16x8*)(lds + (dd) * 32768 + l_ * 128 + kb_); \
        } \
    } \
} while (0)

#define LDB(dd, nh) do { \
    _Pragma("unroll") \
    for (int ni_ = 0; ni_ < 2; ++ni_) { \
        const int l_ = (nh) * 128 + wn * 32 + ni_ * 16 + (lane & 15); \
        _Pragma("unroll") \
        for (int kk_ = 0; kk_ < 2; ++kk_) { \
            const int kb_ = (kk_ * 64 + ((lane >> 4) << 4)) ^ ((lane & 7) << 4); \
            bfr[ni_][kk_] = *(const bf16x8*)(lds + 65536 + (dd) * 32768 + l_ * 128 + kb_); \
        } \
    } \
} while (0)

#define MM(mh, nh) do { \
    __builtin_amdgcn_s_setprio(1); \
    _Pragma("unroll") \
    for (int mi_ = 0; mi_ < 4; ++mi_) \
        _Pragma("unroll") \
        for (int ni_ = 0; ni_ < 2; ++ni_) \
            _Pragma("unroll") \
            for (int kk_ = 0; kk_ < 2; ++kk_) \
                acc[(mh) * 4 + mi_][(nh) * 2 + ni_] = \
                    __builtin_amdgcn_mfma_f32_16x16x32_bf16(af[mi_][kk_], bfr[ni_][kk_], \
                        acc[(mh) * 4 + mi_][(nh) * 2 + ni_], 0, 0, 0); \
    __builtin_amdgcn_s_setprio(0); \
} while (0)

#define BAR()  do { __builtin_amdgcn_sched_barrier(0); __builtin_amdgcn_s_barrier(); __builtin_amdgcn_sched_barrier(0); } while (0)
#define BARW() do { __builtin_amdgcn_sched_barrier(0); asm volatile("s_waitcnt lgkmcnt(0)" ::: "memory"); __builtin_amdgcn_s_barrier(); __builtin_amdgcn_sched_barrier(0); } while (0)
#define VMC(n) asm volatile("s_waitcnt vmcnt(" #n ")" ::: "memory")

#define K_TILE(dd, t) do { \
    bf16x8 af[4][2]; bf16x8 bfr[2][2]; \
    LDA(dd, 0); LDB(dd, 0); STAGE_B((dd) ^ 1, 0, (t) + 1); \
    BAR(); MM(0, 0); BAR(); \
    LDB(dd, 1); STAGE_A(dd, 0, (t) + 2); \
    BAR(); MM(0, 1); BAR(); \
    LDA(dd, 1); STAGE_B(dd, 1, (t) + 2); \
    BAR(); MM(1, 1); BAR(); \
    LDB(dd, 0); STAGE_A(dd, 1, (t) + 2); \
    VMC(6); BAR(); MM(1, 0); BAR(); \
} while (0)

#define RED16(x) do { x += __shfl_xor(x, 1); x += __shfl_xor(x, 2); \
                      x += __shfl_xor(x, 4); x += __shfl_xor(x, 8); } while (0)

__global__ __launch_bounds__(512, 2) void gemm_kv(
    const unsigned short* __restrict__ A,
    const unsigned short* __restrict__ W,
    const float* __restrict__ biasP,
    const float* __restrict__ qkg,
    const float* __restrict__ hid,
    unsigned short* __restrict__ vbuf,
    float* __restrict__ gh2, float* __restrict__ gk2,
    float* __restrict__ ghk, float* __restrict__ gv2)
{
    __shared__ __align__(16) char lds[131072];
    const int tid  = threadIdx.x;
    const int wid  = tid >> 6;
    const int lane = tid & 63;
    const int bid  = blockIdx.x;
    const int swz  = (bid & 7) * 128 + (bid >> 3);   // XCD swizzle, 1024 % 8 == 0
    const int bm = swz >> 4, bn = swz & 15;          // 64 M-tiles x 16 N-tiles
    const int wm = wid >> 2, wn = wid & 3;           // 2 x 4 waves
    const int r0 = bm * 256, c0 = bn * 256;

    const char* Ab = (const char*)A + (size_t)r0 * 2048;
    const char* Wb = (const char*)W + (size_t)c0 * 2048;

    f32x4 acc[8][4] = {};

    // Prologue: tile0 fully + tile1 {A0,B1,A1}; B0(1) is staged in ph1(0).
    STAGE_A(0, 0, 0); STAGE_B(0, 0, 0); STAGE_B(0, 1, 0); STAGE_A(0, 1, 0);
    STAGE_A(1, 0, 1); STAGE_B(1, 1, 1); STAGE_A(1, 1, 1);
    VMC(6);
    BAR();

    for (int t = 0; t < NT_TILES; t += 2) {
        K_TILE(0, t);
        K_TILE(1, t + 1);
    }

    VMC(0);   // drain stragglers before reusing LDS
    BARW();

    float breg[4];
#pragma unroll
    for (int ni = 0; ni < 4; ++ni)
        breg[ni] = biasP[c0 + wn * 64 + ni * 16 + (lane & 15)];

    if (bn < 8) {
        // ---------------- k-half: reduce into per-row h2/k2/hk, no store ----
        float* sH  = (float*)lds;          // [256]
        float* sK  = sH + 256;
        float* sHK = sK + 256;
        for (int i = tid; i < 768; i += 512) sH[i] = 0.0f;
        float qreg[4];
#pragma unroll
        for (int ni = 0; ni < 4; ++ni)
            qreg[ni] = qkg[c0 + wn * 64 + ni * 16 + (lane & 15)];
        BARW();

#pragma unroll
        for (int mi = 0; mi < 8; ++mi) {
            float h2[4] = {}, k2[4] = {}, hk[4] = {};
#pragma unroll
            for (int ni = 0; ni < 4; ++ni) {
#pragma unroll
                for (int j = 0; j < 4; ++j) {
                    const float kv = acc[mi][ni][j] + breg[ni];
                    const int rl = wm * 128 + mi * 16 + (lane >> 4) * 4 + j;
                    const float hv = hid[(size_t)(r0 + rl) * 2048 + c0
                                         + wn * 64 + ni * 16 + (lane & 15)];
                    h2[j] += hv * hv;
                    k2[j] += kv * kv;
                    hk[j] += hv * qreg[ni] * kv;
                }
            }
#pragma unroll
            for (int j = 0; j < 4; ++j) {
                RED16(h2[j]); RED16(k2[j]); RED16(hk[j]);
            }
            if ((lane & 15) == 0) {
#pragma unroll
                for (int j = 0; j < 4; ++j) {
                    const int rl = wm * 128 + mi * 16 + (lane >> 4) * 4 + j;
                    atomicAdd(&sH[rl], h2[j]);
                    atomicAdd(&sK[rl], k2[j]);
                    atomicAdd(&sHK[rl], hk[j]);
                }
            }
        }
        BARW();
        if (tid < 256) {
            atomicAdd(&gh2[r0 + tid], sH[tid]);
            atomicAdd(&gk2[r0 + tid], sK[tid]);
            atomicAdd(&ghk[r0 + tid], sHK[tid]);
        }
    } else {
        // ---------------- v-half: v2 partials + bf16 store ------------------
        float* sV = (float*)(lds + 65536);   // [256], B-region free now
        for (int i = tid; i < 256; i += 512) sV[i] = 0.0f;
        BARW();
        const int cv0 = (bn - 8) * 256;      // col offset within v

#pragma unroll
        for (int mi = 0; mi < 8; ++mi) {
            // v^2 partials from f32 acc
            float v2[4] = {};
#pragma unroll
            for (int ni = 0; ni < 4; ++ni)
#pragma unroll
                for (int j = 0; j < 4; ++j) {
                    const float vv = acc[mi][ni][j] + breg[ni];
                    v2[j] += vv * vv;
                }
#pragma unroll
            for (int j = 0; j < 4; ++j) RED16(v2[j]);
            if ((lane & 15) == 0) {
#pragma unroll
                for (int j = 0; j < 4; ++j) {
                    const int rl = wm * 128 + mi * 16 + (lane >> 4) * 4 + j;
                    atomicAdd(&sV[rl], v2[j]);
                }
            }
            // slab + coalesced store
#pragma unroll
            for (int ni = 0; ni < 4; ++ni) {
#pragma unroll
                for (int j = 0; j < 4; ++j) {
                    const int srow = wm * 16 + (lane >> 4) * 4 + j;
                    const int colb = (wn * 64 + ni * 16 + (lane & 15)) * 2;
                    *(unsigned short*)(lds + srow * 512 + (colb ^ (((srow >> 2) & 3) << 5))) =
                        f2bf(acc[mi][ni][j] + breg[ni]);
                }
            }
            BARW();
#pragma unroll
            for (int c2 = 0; c2 < 4; ++c2) {
                const int lin = c2 * 512 + tid;
                const int srow = lin >> 6, cb8 = (lin & 63) * 8;
                const ushort4 vv = *(const ushort4*)(lds + srow * 512 + (cb8 ^ (((srow >> 2) & 3) << 5)));
                const int grow = r0 + (srow >> 4) * 128 + mi * 16 + (srow & 15);
                const int gcol = cv0 + (lin & 63) * 4;
                *(ushort4*)((char*)vbuf + (size_t)grow * 4096 + gcol * 2) = vv;
            }
            BARW();
        }
        if (tid < 256) atomicAdd(&gv2[r0 + tid], sV[tid]);
    }
}

// ---------------------------------------------------------------------------
// 4) Conv + output, with in-block gate/rinv finalize for the 4 tap rows.
//    out[t,d] = silu( sum_j w[d,j]*gr[rr]*cg[d]*v[rr,d] ) + gate[row]*v[row,d]
// ---------------------------------------------------------------------------
__device__ __forceinline__ void gate_rinv(float h2, float k2, float hk, float v2,
                                          float* gate, float* gr)
{
    const float dot = hk * rsqrtf(h2 * INV_D + EPS_QK) * rsqrtf(k2 * INV_D + EPS_QK)
                      * INV_SQRT_D;
    const float sgn = (dot > 0.f) ? 1.f : ((dot < 0.f) ? -1.f : 0.f);
    const float dd = sqrtf(fmaxf(fabsf(dot), 1e-6f)) * sgn;
    const float g = 1.f / (1.f + expf(-dd));
    *gate = g;
    *gr = g * rsqrtf(g * g * (v2 * INV_D) + EPS_CONV);
}

__global__ __launch_bounds__(256) void convout(
    const unsigned short* __restrict__ vbuf,
    const float* __restrict__ gh2, const float* __restrict__ gk2,
    const float* __restrict__ ghk, const float* __restrict__ gv2,
    const float* __restrict__ cg, const float* __restrict__ convw,
    float* __restrict__ out)
{
    const int row = blockIdx.x;
    const int t   = row & (T_ - 1);
    const int d0  = threadIdx.x * 8;

    // finalize gate*rinv for tap rows (j=3 is row itself)
    float sj[4];
    float g0 = 0.f;
#pragma unroll
    for (int j = 0; j < 4; ++j) {
        const int tau = t - 6 + 2 * j;
        const int rr = row - 6 + 2 * j;
        if (tau < 0) { sj[j] = 0.f; continue; }
        float g, gr;
        gate_rinv(gh2[rr], gk2[rr], ghk[rr], gv2[rr], &g, &gr);
        sj[j] = gr;
        if (j == 3) g0 = g;
    }

    const unsigned short* vrow = vbuf + (size_t)row * D_ + d0;
    const ushort4 v4a = *(const ushort4*)vrow, v4b = *(const ushort4*)(vrow + 4);
    float v[8] = {bf2f(v4a.x), bf2f(v4a.y), bf2f(v4a.z), bf2f(v4a.w),
                  bf2f(v4b.x), bf2f(v4b.y), bf2f(v4b.z), bf2f(v4b.w)};

    const float4 ca = *(const float4*)(cg + d0), cb = *(const float4*)(cg + d0 + 4);
    float cgv[8] = {ca.x, ca.y, ca.z, ca.w, cb.x, cb.y, cb.z, cb.w};

    float w[8][4];
#pragma unroll
    for (int ee = 0; ee < 8; ++ee) {
        const float4 wv = *(const float4*)(convw + (size_t)(d0 + ee) * 4);
        w[ee][0] = wv.x; w[ee][1] = wv.y; w[ee][2] = wv.z; w[ee][3] = wv.w;
    }

    float acc[8] = {};
#pragma unroll
    for (int j = 0; j < 4; ++j) {
        const int tau = t - 6 + 2 * j;
        if (tau < 0) continue;                 // uniform per block
        const int rr = row - 6 + 2 * j;
        const float s = sj[j];
        const unsigned short* vj = vbuf + (size_t)rr * D_ + d0;
        const ushort4 a = *(const ushort4*)vj, b = *(const ushort4*)(vj + 4);
        float vv[8] = {bf2f(a.x), bf2f(a.y), bf2f(a.z), bf2f(a.w),
                       bf2f(b.x), bf2f(b.y), bf2f(b.z), bf2f(b.w)};
#pragma unroll
        for (int ee = 0; ee < 8; ++ee)
            acc[ee] += w[ee][j] * s * cgv[ee] * vv[ee];
    }

    float o[8];
#pragma unroll
    for (int ee = 0; ee < 8; ++ee)
        o[ee] = acc[ee] / (1.f + expf(-acc[ee])) + g0 * v[ee];

    float* op = out + (size_t)row * D_ + d0;
    *(float4*)op       = make_float4(o[0], o[1], o[2], o[3]);
    *(float4*)(op + 4) = make_float4(o[4], o[5], o[6], o[7]);
}

// ---------------------------------------------------------------------------
extern "C" void kernel_launch(void* const* d_in, const int* in_sizes, int n_in,
                              void* d_out, int out_size, void* d_ws, size_t ws_size,
                              hipStream_t stream) {
    const float* hid   = (const float*)d_in[0];
    const int*   hash  = (const int*)  d_in[1];
    const float* table = (const float*)d_in[2];
    const float* kW    = (const float*)d_in[3];
    const float* kb    = (const float*)d_in[4];
    const float* vW    = (const float*)d_in[5];
    const float* vb    = (const float*)d_in[6];
    const float* qg    = (const float*)d_in[7];
    const float* kg    = (const float*)d_in[8];
    const float* cg    = (const float*)d_in[9];
    const float* cw    = (const float*)d_in[10];
    float* out = (float*)d_out;

    char* ws = (char*)d_ws;
    unsigned short* e     = (unsigned short*)(ws);                 //  33,554,432 B
    unsigned short* Wp    = (unsigned short*)(ws + 33554432);      //   8,388,608 B
    float*          biasP = (float*)(ws + 41943040);               //      16,384 B
    float*          qkg   = (float*)(ws + 41959424);               //       8,192 B
    unsigned short* vbuf  = (unsigned short*)(ws + 41967616);      //  67,108,864 B
    float*          gh2   = (float*)(ws + 109076480);              //      65,536 B
    float*          gk2   = (float*)(ws + 109142016);              //      65,536 B
    float*          ghk   = (float*)(ws + 109207552);              //      65,536 B
    float*          gv2   = (float*)(ws + 109273088);              //      65,536 B

    gather_e<<<dim3(NTOK), dim3(256), 0, stream>>>(hash, table, e);
    pack_w<<<dim3(NKV), dim3(256), 0, stream>>>(kW, vW, kb, vb, qg, kg,
                                                Wp, biasP, qkg, gh2 /* 4 contig arrays */);
    gemm_kv<<<dim3(1024), dim3(512), 0, stream>>>(e, Wp, biasP, qkg, hid, vbuf,
                                                  gh2, gk2, ghk, gv2);
    convout<<<dim3(NTOK), dim3(256), 0, stream>>>(vbuf, gh2, gk2, ghk, gv2,
                                                  cg, cw, out);
}

// Round 4
// 250.796 us; speedup vs baseline: 1.7633x; 1.3331x over previous
//
#include <hip/hip_runtime.h>
#include <hip/hip_bf16.h>
#include <math.h>

// Problem constants
#define B_      4
#define T_      4096
#define D_      2048
#define DMEM_   1024
#define H_      16
#define TABLE_  131072
#define NTOK    (B_ * T_)      // 16384 tokens
#define NKV     (2 * D_)       // 4096 packed k|v output columns
#define NT_TILES 16            // K / 64
#define EPS_QK  1.1920928955078125e-07f
#define EPS_CONV 1e-5f
#define INV_D   (1.0f / 2048.0f)
#define INV_SQRT_D 0.02209708691207961f   // 1/sqrt(2048)

typedef __attribute__((ext_vector_type(8))) __bf16 bf16x8;
typedef __attribute__((ext_vector_type(4))) float  f32x4;
typedef __attribute__((ext_vector_type(8))) unsigned short u16x8;

typedef __attribute__((address_space(3))) unsigned int       lds_u32;
typedef const __attribute__((address_space(1))) unsigned int glb_u32;

__device__ __forceinline__ unsigned short f2bf(float f) {
    unsigned u = __float_as_uint(f);
    u += 0x7fff + ((u >> 16) & 1);   // round-to-nearest-even
    return (unsigned short)(u >> 16);
}
__device__ __forceinline__ float bf2f(unsigned short u) {
    return __uint_as_float(((unsigned)u) << 16);
}
__device__ __forceinline__ void gload16(const void* g, void* l) {
    __builtin_amdgcn_global_load_lds((glb_u32*)g, (lds_u32*)l, 16, 0, 0);
}

// 16-lane sum via DPP row_shr (VALU pipe, not LDS). Total lands in lane 15 of
// each 16-lane row.
#define DSHR(x, n) __int_as_float(__builtin_amdgcn_update_dpp( \
    0, __float_as_int(x), 0x110 + (n), 0xf, 0xf, false))
#define RED16(x) do { x += DSHR(x, 1); x += DSHR(x, 2); \
                      x += DSHR(x, 4); x += DSHR(x, 8); } while (0)

// ---------------------------------------------------------------------------
// 1) prep: gather e (bid < NTOK) OR pack W/bias/qkg + zero stats (bid >= NTOK)
// ---------------------------------------------------------------------------
__global__ __launch_bounds__(256) void prep(
    const int* __restrict__ hash_ids, const float* __restrict__ table,
    const float* __restrict__ kW, const float* __restrict__ vW,
    const float* __restrict__ kb, const float* __restrict__ vb,
    const float* __restrict__ qg, const float* __restrict__ kg,
    unsigned short* __restrict__ e, unsigned short* __restrict__ Wp,
    float* __restrict__ biasP, float* __restrict__ qkg,
    float* __restrict__ gstats /* 4*NTOK floats */)
{
    const int bid = blockIdx.x;
    const int tid = threadIdx.x;
    if (bid < NTOK) {
        const int m = tid * 4;
        const int h = m >> 6;
        const int w = m & 63;
        const long long row = (long long)hash_ids[bid * H_ + h] + (long long)h * TABLE_;
        const float4 v = *(const float4*)(table + (size_t)row * 64 + w);
        ushort4 o;
        o.x = f2bf(v.x); o.y = f2bf(v.y); o.z = f2bf(v.z); o.w = f2bf(v.w);
        *(ushort4*)(e + (size_t)bid * DMEM_ + m) = o;
    } else {
        const int n = bid - NTOK;            // 0..4095
        const int m = tid * 4;
        const float* src = (n < D_) ? (kW + (size_t)n * DMEM_) : (vW + (size_t)(n - D_) * DMEM_);
        const float4 v = *(const float4*)(src + m);
        ushort4 o;
        o.x = f2bf(v.x); o.y = f2bf(v.y); o.z = f2bf(v.z); o.w = f2bf(v.w);
        *(ushort4*)(Wp + (size_t)n * DMEM_ + m) = o;
        if (tid == 0) biasP[n] = (n < D_) ? kb[n] : vb[n - D_];
        if (tid == 1 && n < D_) qkg[n] = qg[n] * kg[n];
        if (tid >= 16 && tid < 32) gstats[n * 16 + (tid - 16)] = 0.0f;
    }
}

// ---------------------------------------------------------------------------
// 2) GEMM: 256x256 tile, BK=64, 8 waves (2Mx4N), 8-phase (T2+T3+T4+T5).
//    bn<8  (k-half): reduce tile into per-row {h2,k2,hk} partials, no store.
//    bn>=8 (v-half): store bf16 v to vbuf[16384][2048] + per-row v2 partials.
// ---------------------------------------------------------------------------
#define STAGE_A(dd, mh, ts) do { \
    if ((ts) < NT_TILES) { \
        _Pragma("unroll") \
        for (int c_ = 0; c_ < 2; ++c_) { \
            const int lin_ = c_ * 512 + tid; \
            const int lr_ = lin_ >> 3, c16_ = lin_ & 7; \
            gload16(Ab + (size_t)((lr_ >> 6) * 128 + (mh) * 64 + (lr_ & 63)) * 2048 \
                       + (ts) * 128 + ((c16_ ^ (lr_ & 7)) << 4), \
                    lds + (dd) * 32768 + (mh) * 16384 + (c_ * 512 + wid * 64) * 16); \
        } \
    } \
} while (0)

#define STAGE_B(dd, nh, ts) do { \
    if ((ts) < NT_TILES) { \
        _Pragma("unroll") \
        for (int c_ = 0; c_ < 2; ++c_) { \
            const int lin_ = c_ * 512 + tid; \
            const int lr_ = lin_ >> 3, c16_ = lin_ & 7; \
            gload16(Wb + (size_t)((lr_ >> 5) * 64 + (nh) * 32 + (lr_ & 31)) * 2048 \
                       + (ts) * 128 + ((c16_ ^ (lr_ & 7)) << 4), \
                    lds + 65536 + (dd) * 32768 + (nh) * 16384 + (c_ * 512 + wid * 64) * 16); \
        } \
    } \
} while (0)

#define LDA(dd, mh) do { \
    _Pragma("unroll") \
    for (int mi_ = 0; mi_ < 4; ++mi_) { \
        const int l_ = (mh) * 128 + wm * 64 + mi_ * 16 + (lane & 15); \
        _Pragma("unroll") \
        for (int kk_ = 0; kk_ < 2; ++kk_) { \
            const int kb_ = (kk_ * 64 + ((lane >> 4) << 4)) ^ ((lane & 7) << 4); \
            af[mi_][kk_] = *(const bf16x8*)(lds + (dd) * 32768 + l_ * 128 + kb_); \
        } \
    } \
} while (0)

#define LDB(dd, nh) do { \
    _Pragma("unroll") \
    for (int ni_ = 0; ni_ < 2; ++ni_) { \
        const int l_ = (nh) * 128 + wn * 32 + ni_ * 16 + (lane & 15); \
        _Pragma("unroll") \
        for (int kk_ = 0; kk_ < 2; ++kk_) { \
            const int kb_ = (kk_ * 64 + ((lane >> 4) << 4)) ^ ((lane & 7) << 4); \
            bfr[ni_][kk_] = *(const bf16x8*)(lds + 65536 + (dd) * 32768 + l_ * 128 + kb_); \
        } \
    } \
} while (0)

#define MM(mh, nh) do { \
    __builtin_amdgcn_s_setprio(1); \
    _Pragma("unroll") \
    for (int mi_ = 0; mi_ < 4; ++mi_) \
        _Pragma("unroll") \
        for (int ni_ = 0; ni_ < 2; ++ni_) \
            _Pragma("unroll") \
            for (int kk_ = 0; kk_ < 2; ++kk_) \
                acc[(mh) * 4 + mi_][(nh) * 2 + ni_] = \
                    __builtin_amdgcn_mfma_f32_16x16x32_bf16(af[mi_][kk_], bfr[ni_][kk_], \
                        acc[(mh) * 4 + mi_][(nh) * 2 + ni_], 0, 0, 0); \
    __builtin_amdgcn_s_setprio(0); \
} while (0)

#define BAR()  do { __builtin_amdgcn_sched_barrier(0); __builtin_amdgcn_s_barrier(); __builtin_amdgcn_sched_barrier(0); } while (0)
#define BARW() do { __builtin_amdgcn_sched_barrier(0); asm volatile("s_waitcnt lgkmcnt(0)" ::: "memory"); __builtin_amdgcn_s_barrier(); __builtin_amdgcn_sched_barrier(0); } while (0)
#define VMC(n) asm volatile("s_waitcnt vmcnt(" #n ")" ::: "memory")

#define K_TILE(dd, t) do { \
    bf16x8 af[4][2]; bf16x8 bfr[2][2]; \
    LDA(dd, 0); LDB(dd, 0); STAGE_B((dd) ^ 1, 0, (t) + 1); \
    BAR(); MM(0, 0); BAR(); \
    LDB(dd, 1); STAGE_A(dd, 0, (t) + 2); \
    BAR(); MM(0, 1); BAR(); \
    LDA(dd, 1); STAGE_B(dd, 1, (t) + 2); \
    BAR(); MM(1, 1); BAR(); \
    LDB(dd, 0); STAGE_A(dd, 1, (t) + 2); \
    VMC(6); BAR(); MM(1, 0); BAR(); \
} while (0)

__global__ __launch_bounds__(512, 2) void gemm_kv(
    const unsigned short* __restrict__ A,
    const unsigned short* __restrict__ W,
    const float* __restrict__ biasP,
    const float* __restrict__ qkg,
    const float* __restrict__ hid,
    unsigned short* __restrict__ vbuf,
    float* __restrict__ gh2, float* __restrict__ gk2,
    float* __restrict__ ghk, float* __restrict__ gv2)
{
    __shared__ __align__(16) char lds[131072];
    const int tid  = threadIdx.x;
    const int wid  = tid >> 6;
    const int lane = tid & 63;
    const int bid  = blockIdx.x;
    const int swz  = (bid & 7) * 128 + (bid >> 3);   // XCD swizzle, 1024 % 8 == 0
    const int bm = swz >> 4, bn = swz & 15;          // 64 M-tiles x 16 N-tiles
    const int wm = wid >> 2, wn = wid & 3;           // 2 x 4 waves
    const int r0 = bm * 256, c0 = bn * 256;

    const char* Ab = (const char*)A + (size_t)r0 * 2048;
    const char* Wb = (const char*)W + (size_t)c0 * 2048;

    f32x4 acc[8][4] = {};

    // Prologue: tile0 fully + tile1 {A0,B1,A1}; B0(1) is staged in ph1(0).
    STAGE_A(0, 0, 0); STAGE_B(0, 0, 0); STAGE_B(0, 1, 0); STAGE_A(0, 1, 0);
    STAGE_A(1, 0, 1); STAGE_B(1, 1, 1); STAGE_A(1, 1, 1);
    VMC(6);
    BAR();

    for (int t = 0; t < NT_TILES; t += 2) {
        K_TILE(0, t);
        K_TILE(1, t + 1);
    }

    VMC(0);   // drain stragglers before reusing LDS
    BARW();

    float breg[4];
#pragma unroll
    for (int ni = 0; ni < 4; ++ni)
        breg[ni] = biasP[c0 + wn * 64 + ni * 16 + (lane & 15)];

    if (bn < 8) {
        // ---------------- k-half: reduce into per-row h2/k2/hk, no store ----
        float* sH  = (float*)lds;          // [256]
        float* sK  = sH + 256;
        float* sHK = sK + 256;
        for (int i = tid; i < 768; i += 512) sH[i] = 0.0f;
        float qreg[4];
#pragma unroll
        for (int ni = 0; ni < 4; ++ni)
            qreg[ni] = qkg[c0 + wn * 64 + ni * 16 + (lane & 15)];
        BARW();

#pragma unroll
        for (int mi = 0; mi < 8; ++mi) {
            float h2[4] = {}, k2[4] = {}, hk[4] = {};
#pragma unroll
            for (int ni = 0; ni < 4; ++ni) {
#pragma unroll
                for (int j = 0; j < 4; ++j) {
                    const float kv = acc[mi][ni][j] + breg[ni];
                    const int rl = wm * 128 + mi * 16 + (lane >> 4) * 4 + j;
                    const float hv = hid[(size_t)(r0 + rl) * 2048 + c0
                                         + wn * 64 + ni * 16 + (lane & 15)];
                    h2[j] += hv * hv;
                    k2[j] += kv * kv;
                    hk[j] += hv * qreg[ni] * kv;
                }
            }
#pragma unroll
            for (int j = 0; j < 4; ++j) {
                RED16(h2[j]); RED16(k2[j]); RED16(hk[j]);
            }
            if ((lane & 15) == 15) {
#pragma unroll
                for (int j = 0; j < 4; ++j) {
                    const int rl = wm * 128 + mi * 16 + (lane >> 4) * 4 + j;
                    atomicAdd(&sH[rl], h2[j]);
                    atomicAdd(&sK[rl], k2[j]);
                    atomicAdd(&sHK[rl], hk[j]);
                }
            }
        }
        BARW();
        if (tid < 256) {
            atomicAdd(&gh2[r0 + tid], sH[tid]);
            atomicAdd(&gk2[r0 + tid], sK[tid]);
            atomicAdd(&ghk[r0 + tid], sHK[tid]);
        }
    } else {
        // ---------------- v-half: v2 partials + bf16 store ------------------
        float* sV = (float*)(lds + 65536);   // [256], B-region free now
        for (int i = tid; i < 256; i += 512) sV[i] = 0.0f;
        BARW();
        const int cv0 = (bn - 8) * 256;      // col offset within v

#pragma unroll
        for (int mi = 0; mi < 8; ++mi) {
            // v^2 partials from f32 acc
            float v2[4] = {};
#pragma unroll
            for (int ni = 0; ni < 4; ++ni)
#pragma unroll
                for (int j = 0; j < 4; ++j) {
                    const float vv = acc[mi][ni][j] + breg[ni];
                    v2[j] += vv * vv;
                }
#pragma unroll
            for (int j = 0; j < 4; ++j) RED16(v2[j]);
            if ((lane & 15) == 15) {
#pragma unroll
                for (int j = 0; j < 4; ++j) {
                    const int rl = wm * 128 + mi * 16 + (lane >> 4) * 4 + j;
                    atomicAdd(&sV[rl], v2[j]);
                }
            }
            // slab + coalesced store
#pragma unroll
            for (int ni = 0; ni < 4; ++ni) {
#pragma unroll
                for (int j = 0; j < 4; ++j) {
                    const int srow = wm * 16 + (lane >> 4) * 4 + j;
                    const int colb = (wn * 64 + ni * 16 + (lane & 15)) * 2;
                    *(unsigned short*)(lds + srow * 512 + (colb ^ (((srow >> 2) & 3) << 5))) =
                        f2bf(acc[mi][ni][j] + breg[ni]);
                }
            }
            BARW();
#pragma unroll
            for (int c2 = 0; c2 < 4; ++c2) {
                const int lin = c2 * 512 + tid;
                const int srow = lin >> 6, cb8 = (lin & 63) * 8;
                const ushort4 vv = *(const ushort4*)(lds + srow * 512 + (cb8 ^ (((srow >> 2) & 3) << 5)));
                const int grow = r0 + (srow >> 4) * 128 + mi * 16 + (srow & 15);
                const int gcol = cv0 + (lin & 63) * 4;
                *(ushort4*)((char*)vbuf + (size_t)grow * 4096 + gcol * 2) = vv;
            }
            BARW();
        }
        if (tid < 256) atomicAdd(&gv2[r0 + tid], sV[tid]);
    }
}

// ---------------------------------------------------------------------------
// 3) finalize: stats -> gate[row], gr[row] = gate*rinv
// ---------------------------------------------------------------------------
__global__ __launch_bounds__(256) void finalize(
    const float* __restrict__ gh2, const float* __restrict__ gk2,
    const float* __restrict__ ghk, const float* __restrict__ gv2,
    float* __restrict__ gateb, float* __restrict__ grb)
{
    const int i = blockIdx.x * 256 + threadIdx.x;
    const float dot = ghk[i] * rsqrtf(gh2[i] * INV_D + EPS_QK)
                             * rsqrtf(gk2[i] * INV_D + EPS_QK) * INV_SQRT_D;
    const float sgn = (dot > 0.f) ? 1.f : ((dot < 0.f) ? -1.f : 0.f);
    const float dd = sqrtf(fmaxf(fabsf(dot), 1e-6f)) * sgn;
    const float g = 1.f / (1.f + expf(-dd));
    gateb[i] = g;
    grb[i] = g * rsqrtf(g * g * (gv2[i] * INV_D) + EPS_CONV);
}

// ---------------------------------------------------------------------------
// 4) convout, row-tiled: 16 out rows x 256 cols per block; 22 v-rows staged
//    in LDS. out[t,d] = silu(sum_j w[d,j]*gr[rr]*cg[d]*v[rr,d]) + gate*v[t,d]
// ---------------------------------------------------------------------------
__global__ __launch_bounds__(256) void convout(
    const unsigned short* __restrict__ vbuf,
    const float* __restrict__ gateb, const float* __restrict__ grb,
    const float* __restrict__ cg, const float* __restrict__ convw,
    float* __restrict__ out)
{
    __shared__ __align__(16) char vlds[22 * 512];
    const int bid = blockIdx.x;
    const int by = bid >> 3, bx = bid & 7;
    const int R0 = by * 16, C0 = bx * 256;
    const int tid = threadIdx.x;

    // stage rows R0-6 .. R0+15, cols C0..C0+255 (bf16), 11264 B in 3 chunks
#pragma unroll
    for (int c = 0; c < 3; ++c) {
        const int wbase = c * 4096 + (tid >> 6) * 1024;   // wave-uniform dest
        if (wbase < 11264) {
            const int off = c * 4096 + tid * 16;
            const int i = off >> 9;
            int g = R0 - 6 + i; if (g < 0) g = 0;
            gload16((const char*)vbuf + (size_t)g * 4096 + C0 * 2 + (off & 511),
                    vlds + wbase);
        }
    }
    VMC(0);
    __syncthreads();

    const int cgrp = tid & 31;          // 8-col group
    const int rgrp = tid >> 5;          // 0..7 -> rows 2*rgrp, 2*rgrp+1
    const int dcol = C0 + cgrp * 8;
    const int cb = cgrp * 16;           // byte offset in an LDS row

    const float4 ca = *(const float4*)(cg + dcol), cbv = *(const float4*)(cg + dcol + 4);
    const float cgv[8] = {ca.x, ca.y, ca.z, ca.w, cbv.x, cbv.y, cbv.z, cbv.w};
    float w[8][4];
#pragma unroll
    for (int ee = 0; ee < 8; ++ee) {
        const float4 wv = *(const float4*)(convw + (size_t)(dcol + ee) * 4);
        w[ee][0] = wv.x; w[ee][1] = wv.y; w[ee][2] = wv.z; w[ee][3] = wv.w;
    }

#pragma unroll
    for (int rr = 0; rr < 2; ++rr) {
        const int rloc = rgrp * 2 + rr;          // 0..15
        const int row = R0 + rloc;
        const int t = row & (T_ - 1);
        const float g0 = gateb[row];

        float acc[8] = {};
#pragma unroll
        for (int j = 0; j < 4; ++j) {
            const int tau = t - 6 + 2 * j;
            if (tau < 0) continue;
            const float s = grb[row - 6 + 2 * j];
            const u16x8 vv = *(const u16x8*)(vlds + (rloc + 2 * j) * 512 + cb);
#pragma unroll
            for (int ee = 0; ee < 8; ++ee)
                acc[ee] += w[ee][j] * s * cgv[ee] * bf2f(vv[ee]);
        }

        const u16x8 vown = *(const u16x8*)(vlds + (rloc + 6) * 512 + cb);
        float o[8];
#pragma unroll
        for (int ee = 0; ee < 8; ++ee)
            o[ee] = acc[ee] / (1.f + expf(-acc[ee])) + g0 * bf2f(vown[ee]);

        float* op = out + (size_t)row * D_ + dcol;
        *(float4*)op       = make_float4(o[0], o[1], o[2], o[3]);
        *(float4*)(op + 4) = make_float4(o[4], o[5], o[6], o[7]);
    }
}

// ---------------------------------------------------------------------------
extern "C" void kernel_launch(void* const* d_in, const int* in_sizes, int n_in,
                              void* d_out, int out_size, void* d_ws, size_t ws_size,
                              hipStream_t stream) {
    const float* hid   = (const float*)d_in[0];
    const int*   hash  = (const int*)  d_in[1];
    const float* table = (const float*)d_in[2];
    const float* kW    = (const float*)d_in[3];
    const float* kb    = (const float*)d_in[4];
    const float* vW    = (const float*)d_in[5];
    const float* vb    = (const float*)d_in[6];
    const float* qg    = (const float*)d_in[7];
    const float* kg    = (const float*)d_in[8];
    const float* cg    = (const float*)d_in[9];
    const float* cw    = (const float*)d_in[10];
    float* out = (float*)d_out;

    char* ws = (char*)d_ws;
    unsigned short* e     = (unsigned short*)(ws);                 //  33,554,432 B
    unsigned short* Wp    = (unsigned short*)(ws + 33554432);      //   8,388,608 B
    float*          biasP = (float*)(ws + 41943040);               //      16,384 B
    float*          qkg   = (float*)(ws + 41959424);               //       8,192 B
    unsigned short* vbuf  = (unsigned short*)(ws + 41967616);      //  67,108,864 B
    float*          gh2   = (float*)(ws + 109076480);              //      65,536 B
    float*          gk2   = (float*)(ws + 109142016);              //      65,536 B
    float*          ghk   = (float*)(ws + 109207552);              //      65,536 B
    float*          gv2   = (float*)(ws + 109273088);              //      65,536 B
    float*          gateb = (float*)(ws + 109338624);              //      65,536 B
    float*          grb   = (float*)(ws + 109404160);              //      65,536 B

    prep<<<dim3(NTOK + NKV), dim3(256), 0, stream>>>(hash, table, kW, vW, kb, vb,
                                                     qg, kg, e, Wp, biasP, qkg, gh2);
    gemm_kv<<<dim3(1024), dim3(512), 0, stream>>>(e, Wp, biasP, qkg, hid, vbuf,
                                                  gh2, gk2, ghk, gv2);
    finalize<<<dim3(64), dim3(256), 0, stream>>>(gh2, gk2, ghk, gv2, gateb, grb);
    convout<<<dim3(8192), dim3(256), 0, stream>>>(vbuf, gateb, grb, cg, cw, out);
}